// Round 3
// baseline (40.168 us; speedup 1.0000x reference)
//
#include <hip/hip_runtime.h>
#include <math.h>

#define DD 128
#define BB 8192
#define NNEG 5
#define LL 10

__device__ __forceinline__ float log_sigmoid(float x) {
    // stable: min(x,0) - log1p(exp(-|x|))
    return fminf(x, 0.0f) - log1pf(expf(-fabsf(x)));
}

__device__ __forceinline__ void f4add(float4& a, const float4 b) {
    a.x += b.x; a.y += b.y; a.z += b.z; a.w += b.w;
}

// One wave per batch element. Lanes: half = lane>>5 picks even/odd row of an
// index pair, lq = lane&31 owns dims 4*lq..4*lq+3 (float4). A single dwordx4
// gather instruction thus covers 2 rows (1 KB).
//
// Key changes vs R2:
//  - b is readfirstlane'd -> all index/len loads become scalar (s_load),
//    freeing the VMEM pipe for gathers only.
//  - wave-uniform pair-skip: pair s is loaded only if 2s < len (len is
//    wave-uniform -> s_cbranch, no divergence). Cuts ~40% of gather
//    instructions (the all-pad pairs that fetched the zero row).
//  - guarded loads land in separate zero-init temporaries; all accumulation
//    happens after, so taken loads still issue back-to-back (full MLP).
extern "C" __global__ void __launch_bounds__(256, 6)
n2v_main(const float* __restrict__ u_table,
         const float* __restrict__ v_table,
         const int* __restrict__ pos_u,
         const int* __restrict__ pos_u_lens,
         const int* __restrict__ pos_v,
         const int* __restrict__ pos_v_lens,
         const int* __restrict__ neg_v,
         const int* __restrict__ neg_v_lens,
         float* __restrict__ partial)   // [BB] per-element loss contribution
{
    const int lane = threadIdx.x & 63;
    const int half = lane >> 5;   // 0: even row of pair, 1: odd row
    const int lq   = lane & 31;   // float4 slot within the 128-dim row
    const int b    = __builtin_amdgcn_readfirstlane(
                         blockIdx.x * 4 + (threadIdx.x >> 6));

    const float4* __restrict__ ut4 = (const float4*)u_table;
    const float4* __restrict__ vt4 = (const float4*)v_table;

    // scalar prefetch of lens (b uniform -> s_load)
    const int len_u = pos_u_lens[b];
    const int len_v = pos_v_lens[b];
    int len_n[NNEG];
    #pragma unroll
    for (int n = 0; n < NNEG; ++n) len_n[n] = neg_v_lens[b * NNEG + n];

    // ---- emb_u[b] ----
    float4 eu;
    {
        float4 t[LL / 2];
        #pragma unroll
        for (int s = 0; s < LL / 2; ++s) t[s] = make_float4(0.f, 0.f, 0.f, 0.f);
        const int* pu = pos_u + b * LL;
        #pragma unroll
        for (int s = 0; s < LL / 2; ++s) {
            if (2 * s < len_u) {                       // wave-uniform guard
                const int2 ii = *(const int2*)(pu + 2 * s);  // scalar load
                const int idx = half ? ii.y : ii.x;
                t[s] = ut4[idx * (DD / 4) + lq];
            }
        }
        f4add(t[0], t[1]); f4add(t[2], t[3]); f4add(t[0], t[2]); f4add(t[0], t[4]);
        eu = t[0];
        eu.x += __shfl_xor(eu.x, 32, 64);
        eu.y += __shfl_xor(eu.y, 32, 64);
        eu.z += __shfl_xor(eu.z, 32, 64);
        eu.w += __shfl_xor(eu.w, 32, 64);
        const float inv = 1.0f / (float)len_u;
        eu.x *= inv; eu.y *= inv; eu.z *= inv; eu.w *= inv;
    }

    // ---- emb_v[b] ----
    float4 ev;
    {
        float4 t[LL / 2];
        #pragma unroll
        for (int s = 0; s < LL / 2; ++s) t[s] = make_float4(0.f, 0.f, 0.f, 0.f);
        const int* pv = pos_v + b * LL;
        #pragma unroll
        for (int s = 0; s < LL / 2; ++s) {
            if (2 * s < len_v) {
                const int2 ii = *(const int2*)(pv + 2 * s);
                const int idx = half ? ii.y : ii.x;
                t[s] = vt4[idx * (DD / 4) + lq];
            }
        }
        f4add(t[0], t[1]); f4add(t[2], t[3]); f4add(t[0], t[2]); f4add(t[0], t[4]);
        ev = t[0];
        ev.x += __shfl_xor(ev.x, 32, 64);
        ev.y += __shfl_xor(ev.y, 32, 64);
        ev.z += __shfl_xor(ev.z, 32, 64);
        ev.w += __shfl_xor(ev.w, 32, 64);
        const float inv = 1.0f / (float)len_v;
        ev.x *= inv; ev.y *= inv; ev.z *= inv; ev.w *= inv;
    }

    // ---- positive score ----
    float p = eu.x * ev.x + eu.y * ev.y + eu.z * ev.z + eu.w * ev.w;
    #pragma unroll
    for (int off = 16; off > 0; off >>= 1) p += __shfl_xor(p, off, 64);
    float acc = log_sigmoid(p);

    // ---- negatives ----
    const int* nv = neg_v + b * NNEG * LL;
    #pragma unroll
    for (int n = 0; n < NNEG; ++n) {
        float4 t[LL / 2];
        #pragma unroll
        for (int s = 0; s < LL / 2; ++s) t[s] = make_float4(0.f, 0.f, 0.f, 0.f);
        #pragma unroll
        for (int s = 0; s < LL / 2; ++s) {
            if (2 * s < len_n[n]) {
                const int2 ii = *(const int2*)(nv + n * LL + 2 * s);
                const int idx = half ? ii.y : ii.x;
                t[s] = vt4[idx * (DD / 4) + lq];
            }
        }
        f4add(t[0], t[1]); f4add(t[2], t[3]); f4add(t[0], t[2]); f4add(t[0], t[4]);
        float4 a = t[0];
        a.x += __shfl_xor(a.x, 32, 64);
        a.y += __shfl_xor(a.y, 32, 64);
        a.z += __shfl_xor(a.z, 32, 64);
        a.w += __shfl_xor(a.w, 32, 64);
        float q = a.x * eu.x + a.y * eu.y + a.z * eu.z + a.w * eu.w;
        #pragma unroll
        for (int off = 16; off > 0; off >>= 1) q += __shfl_xor(q, off, 64);
        const float ns = q / (float)len_n[n];
        acc += log_sigmoid(-ns);
    }

    if (lane == 0) partial[b] = -acc * (1.0f / (float)BB);
}

// Single-block tree reduction of the 8192 partials -> out[0]. No atomics.
extern "C" __global__ void __launch_bounds__(1024)
n2v_reduce(const float* __restrict__ partial, float* __restrict__ out)
{
    float s = 0.f;
    const float4* p4 = (const float4*)partial;
    #pragma unroll
    for (int i = threadIdx.x; i < BB / 4; i += 1024) {
        const float4 v = p4[i];
        s += v.x + v.y + v.z + v.w;
    }
    #pragma unroll
    for (int off = 32; off > 0; off >>= 1) s += __shfl_xor(s, off, 64);
    __shared__ float ls[16];
    const int w = threadIdx.x >> 6;
    if ((threadIdx.x & 63) == 0) ls[w] = s;
    __syncthreads();
    if (threadIdx.x == 0) {
        float t = 0.f;
        #pragma unroll
        for (int i = 0; i < 16; ++i) t += ls[i];
        out[0] = t;
    }
}

extern "C" void kernel_launch(void* const* d_in, const int* in_sizes, int n_in,
                              void* d_out, int out_size, void* d_ws, size_t ws_size,
                              hipStream_t stream) {
    const float* u_table    = (const float*)d_in[0];
    const float* v_table    = (const float*)d_in[1];
    const int*   pos_u      = (const int*)d_in[2];
    const int*   pos_u_lens = (const int*)d_in[3];
    const int*   pos_v      = (const int*)d_in[4];
    const int*   pos_v_lens = (const int*)d_in[5];
    const int*   neg_v      = (const int*)d_in[6];
    const int*   neg_v_lens = (const int*)d_in[7];
    float*       out        = (float*)d_out;
    float*       partial    = (float*)d_ws;   // 8192 floats, fully overwritten

    n2v_main<<<dim3(BB / 4), dim3(256), 0, stream>>>(
        u_table, v_table, pos_u, pos_u_lens, pos_v, pos_v_lens,
        neg_v, neg_v_lens, partial);
    n2v_reduce<<<dim3(1), dim3(1024), 0, stream>>>(partial, out);
}

// Round 4
// 36.462 us; speedup vs baseline: 1.1017x; 1.1017x over previous
//
#include <hip/hip_runtime.h>
#include <math.h>

#define DD 128
#define BB 8192
#define NNEG 5
#define LL 10

__device__ __forceinline__ float log_sigmoid(float x) {
    // stable: min(x,0) - log1p(exp(-|x|))
    return fminf(x, 0.0f) - log1pf(expf(-fabsf(x)));
}

__device__ __forceinline__ void f4add(float4& a, const float4 b) {
    a.x += b.x; a.y += b.y; a.z += b.z; a.w += b.w;
}

// Sum of 10 table rows (5 index pairs), one wave: half=lane>>5 picks the
// even/odd row of each pair, lq=lane&31 owns dims 4lq..4lq+3. ids is a
// wave-uniform pointer (derived from readfirstlane'd b) -> the index reads
// compile to s_load (SMEM pipe), keeping the VMEM pipe 100% gathers.
// Branchless: pad indices load the all-zero row 0 (L1-resident, free-ish).
__device__ __forceinline__ float4 bag_sum(const float4* __restrict__ tab,
                                          const int* __restrict__ ids,
                                          int half, int lq)
{
    int sel[LL / 2];
    #pragma unroll
    for (int s = 0; s < LL / 2; ++s) {
        const int e = ids[2 * s];       // uniform -> s_load
        const int o = ids[2 * s + 1];   // uniform -> s_load
        sel[s] = half ? o : e;          // v_cndmask between two SGPRs
    }
    float4 t[LL / 2];
    #pragma unroll
    for (int s = 0; s < LL / 2; ++s)
        t[s] = tab[sel[s] * (DD / 4) + lq];   // 5 gathers, back-to-back
    f4add(t[0], t[1]); f4add(t[2], t[3]); f4add(t[0], t[2]); f4add(t[0], t[4]);
    // combine even/odd-row halves
    t[0].x += __shfl_xor(t[0].x, 32, 64);
    t[0].y += __shfl_xor(t[0].y, 32, 64);
    t[0].z += __shfl_xor(t[0].z, 32, 64);
    t[0].w += __shfl_xor(t[0].w, 32, 64);
    return t[0];
}

extern "C" __global__ void __launch_bounds__(256, 8)
n2v_main(const float* __restrict__ u_table,
         const float* __restrict__ v_table,
         const int* __restrict__ pos_u,
         const int* __restrict__ pos_u_lens,
         const int* __restrict__ pos_v,
         const int* __restrict__ pos_v_lens,
         const int* __restrict__ neg_v,
         const int* __restrict__ neg_v_lens,
         float* __restrict__ partial)   // [BB] per-element loss contribution
{
    const int lane = threadIdx.x & 63;
    const int half = lane >> 5;
    const int lq   = lane & 31;
    const int b    = __builtin_amdgcn_readfirstlane(
                         blockIdx.x * 4 + (threadIdx.x >> 6));

    const float4* __restrict__ ut4 = (const float4*)u_table;
    const float4* __restrict__ vt4 = (const float4*)v_table;

    // ---- emb_u[b], emb_v[b] ----
    float4 eu = bag_sum(ut4, pos_u + b * LL, half, lq);
    {
        const float inv = 1.0f / (float)pos_u_lens[b];   // s_load
        eu.x *= inv; eu.y *= inv; eu.z *= inv; eu.w *= inv;
    }
    float4 ev = bag_sum(vt4, pos_v + b * LL, half, lq);
    {
        const float inv = 1.0f / (float)pos_v_lens[b];
        ev.x *= inv; ev.y *= inv; ev.z *= inv; ev.w *= inv;
    }

    // ---- positive score ----
    float p = eu.x * ev.x + eu.y * ev.y + eu.z * ev.z + eu.w * ev.w;
    #pragma unroll
    for (int off = 16; off > 0; off >>= 1) p += __shfl_xor(p, off, 64);
    float acc = log_sigmoid(p);

    // ---- negatives ----
    const int* nv = neg_v + b * (NNEG * LL);
    #pragma unroll
    for (int n = 0; n < NNEG; ++n) {
        const float4 a = bag_sum(vt4, nv + n * LL, half, lq);
        float q = a.x * eu.x + a.y * eu.y + a.z * eu.z + a.w * eu.w;
        #pragma unroll
        for (int off = 16; off > 0; off >>= 1) q += __shfl_xor(q, off, 64);
        const float ns = q / (float)neg_v_lens[b * NNEG + n];   // s_load
        acc += log_sigmoid(-ns);
    }

    if (lane == 0) partial[b] = -acc * (1.0f / (float)BB);
}

// Single-block tree reduction of the 8192 partials -> out[0]. No atomics.
extern "C" __global__ void __launch_bounds__(1024)
n2v_reduce(const float* __restrict__ partial, float* __restrict__ out)
{
    float s = 0.f;
    const float4* p4 = (const float4*)partial;
    #pragma unroll
    for (int i = threadIdx.x; i < BB / 4; i += 1024) {
        const float4 v = p4[i];
        s += v.x + v.y + v.z + v.w;
    }
    #pragma unroll
    for (int off = 32; off > 0; off >>= 1) s += __shfl_xor(s, off, 64);
    __shared__ float ls[16];
    const int w = threadIdx.x >> 6;
    if ((threadIdx.x & 63) == 0) ls[w] = s;
    __syncthreads();
    if (threadIdx.x == 0) {
        float t = 0.f;
        #pragma unroll
        for (int i = 0; i < 16; ++i) t += ls[i];
        out[0] = t;
    }
}

extern "C" void kernel_launch(void* const* d_in, const int* in_sizes, int n_in,
                              void* d_out, int out_size, void* d_ws, size_t ws_size,
                              hipStream_t stream) {
    const float* u_table    = (const float*)d_in[0];
    const float* v_table    = (const float*)d_in[1];
    const int*   pos_u      = (const int*)d_in[2];
    const int*   pos_u_lens = (const int*)d_in[3];
    const int*   pos_v      = (const int*)d_in[4];
    const int*   pos_v_lens = (const int*)d_in[5];
    const int*   neg_v      = (const int*)d_in[6];
    const int*   neg_v_lens = (const int*)d_in[7];
    float*       out        = (float*)d_out;
    float*       partial    = (float*)d_ws;   // 8192 floats, fully overwritten

    n2v_main<<<dim3(BB / 4), dim3(256), 0, stream>>>(
        u_table, v_table, pos_u, pos_u_lens, pos_v, pos_v_lens,
        neg_v, neg_v_lens, partial);
    n2v_reduce<<<dim3(1), dim3(1024), 0, stream>>>(partial, out);
}